// Round 5
// baseline (467.651 us; speedup 1.0000x reference)
//
#include <hip/hip_runtime.h>
#include <hip/hip_cooperative_groups.h>

namespace cg = cooperative_groups;

// B=4, N=2048, C=256, ic=128.  Algebra (validated rounds 1-3):
//   T=lin(aim,theta) P=lin(detect,phi) Gd=lin(detect,g) Ga=lin(aim,g2)   [bf16]
//   X_v := per-batch view [128,4096] of [2048,256] (pure reshape)
//   S_aT = Gd_v @ P_v^T ; S_bT = Ga_v @ T_v^T        [128,128] fp32 (split-K + reduce)
//   NA_v = S_aT @ T_v /4096 ; ND_v = S_bT @ P_v /4096  [bf16]
//   out_aim = lin(NA,W)+aim ; out_det = lin(ND,Q)+detect  (fp32, order: det,aim)
// Round 5: cooperative mega-kernel with LDS <= 28 KB/block (round-4's 52 KB
// exceeded the runtime's 64 KB/CU co-residency budget at 2 blocks/CU, so the
// 512-block cooperative launch was rejected silently). Return code now checked;
// fallback = round-3's six-kernel path (passing at 137.9 us).

typedef __attribute__((ext_vector_type(4))) float  f32x4;
typedef __attribute__((ext_vector_type(8))) __bf16 bf16x8;
typedef __attribute__((ext_vector_type(8))) unsigned short u16x8;
typedef __attribute__((ext_vector_type(4))) unsigned short u16x4;

__device__ inline unsigned short f2bf(float f) {
    union { float f; unsigned u; } c; c.f = f;
    unsigned r = c.u + 0x7FFF + ((c.u >> 16) & 1);   // RNE
    return (unsigned short)(r >> 16);
}
__device__ inline bf16x8 ldfrag(const unsigned short* p) {
    return __builtin_bit_cast(bf16x8, *(const u16x8*)p);
}

struct Params {
    const float *detect, *aim;
    const float *g_w, *g2_w, *th_w, *ph_w, *W_w, *Q_w;
    const float *g_b, *g2_b, *th_b, *ph_b, *W_b, *Q_b;
    unsigned short *Wbf, *Abf, *Dbf, *T, *P, *Gd, *Ga, *NA, *ND;
    float *S, *Spart;
    float *out_det, *out_aim;
};

// ======================= cooperative mega-kernel =============================
__global__ __launch_bounds__(256, 2)
void mega_kernel(Params p)
{
    cg::grid_group grid = cg::this_grid();
    const int bx = blockIdx.x, tid = threadIdx.x;
    const int lane = tid & 63, w = tid >> 6;
    const int wr = w >> 1, wc = w & 1, q = lane >> 4, ln = lane & 15;

    __shared__ union {
        struct { unsigned short As[64][40];  unsigned short Bs[256][40]; } lin;  // 25.6 KB
        struct { unsigned short As[128][40]; unsigned short Bs[128][40]; } sp;   // 20.5 KB
        struct { unsigned short As[128][72]; unsigned short Bs[64][72];  } nd;   // 27.7 KB
        struct { unsigned short As[64][40];  unsigned short Bs[128][40]; } fin;  // 15.4 KB
    } sm;

    // ---------------- P0: fp32 -> bf16 conversion (weights + inputs) ---------
    {
        const int z = bx >> 6, sub = bx & 63;
        const float* src; size_t n4; unsigned short* o;
        switch (z) {
            case 0: src = p.g_w;    n4 = 16384;  o = p.Wbf;             break;
            case 1: src = p.g2_w;   n4 = 16384;  o = p.Wbf + 65536;     break;
            case 2: src = p.th_w;   n4 = 16384;  o = p.Wbf + 2*65536;   break;
            case 3: src = p.ph_w;   n4 = 16384;  o = p.Wbf + 3*65536;   break;
            case 4: src = p.W_w;    n4 = 16384;  o = p.Wbf + 4*65536;   break;
            case 5: src = p.Q_w;    n4 = 16384;  o = p.Wbf + 5*65536;   break;
            case 6: src = p.aim;    n4 = 524288; o = p.Abf;             break;
            default:src = p.detect; n4 = 524288; o = p.Dbf;             break;
        }
        for (size_t i = (size_t)sub * 256 + tid; i < n4; i += 64 * 256) {
            float4 v = ((const float4*)src)[i];
            u16x4 pk; pk[0]=f2bf(v.x); pk[1]=f2bf(v.y); pk[2]=f2bf(v.z); pk[3]=f2bf(v.w);
            ((u16x4*)o)[i] = pk;
        }
    }
    grid.sync();

    // ---------------- P1: four input linears (64x256 tile, BK=32) ------------
    {
        const int set = bx & 1, z = (bx >> 1) & 1;
        const int m0 = (bx >> 2) * 64;
        const unsigned short* A = z ? p.Dbf : p.Abf;
        const int wslot = z ? (set ? 0 : 3) : (set ? 1 : 2);   // g / ph / g2 / th
        const unsigned short* Wm = p.Wbf + (size_t)wslot * 65536;
        const float* Bv = z ? (set ? p.g_b : p.ph_b) : (set ? p.g2_b : p.th_b);
        unsigned short* O = z ? (set ? p.Gd : p.P) : (set ? p.Ga : p.T);

        f32x4 acc[2][8] = {};
        for (int k0 = 0; k0 < 256; k0 += 32) {
            {
                int row = tid >> 2, c8 = tid & 3;
                *(u16x8*)&sm.lin.As[row][c8 * 8] =
                    *(const u16x8*)(A + (size_t)(m0 + row) * 256 + k0 + c8 * 8);
            }
            #pragma unroll
            for (int i = 0; i < 4; ++i) {
                int c = tid + i * 256, row = c >> 2, c8 = c & 3;
                *(u16x8*)&sm.lin.Bs[row][c8 * 8] =
                    *(const u16x8*)(Wm + (size_t)row * 256 + k0 + c8 * 8);
            }
            __syncthreads();
            bf16x8 af[2], bb[8];
            #pragma unroll
            for (int i = 0; i < 2; ++i) af[i] = ldfrag(&sm.lin.As[wr * 32 + i * 16 + ln][q * 8]);
            #pragma unroll
            for (int j = 0; j < 8; ++j) bb[j] = ldfrag(&sm.lin.Bs[wc * 128 + j * 16 + ln][q * 8]);
            #pragma unroll
            for (int i = 0; i < 2; ++i)
                #pragma unroll
                for (int j = 0; j < 8; ++j)
                    acc[i][j] = __builtin_amdgcn_mfma_f32_16x16x32_bf16(af[i], bb[j], acc[i][j], 0, 0, 0);
            __syncthreads();
        }
        #pragma unroll
        for (int i = 0; i < 2; ++i)
            #pragma unroll
            for (int j = 0; j < 8; ++j) {
                int n = wc * 128 + j * 16 + ln;
                float bias = Bv[n];
                #pragma unroll
                for (int r = 0; r < 4; ++r) {
                    int m = m0 + wr * 32 + i * 16 + q * 4 + r;
                    O[(size_t)m * 256 + n] = f2bf(acc[i][j][r] + bias);
                }
            }
    }
    grid.sync();

    // ---------------- P2: S partials, split-K (blocks 0..255, BK=32) ---------
    if (bx < 256) {
        const int which = bx >> 7, rem = bx & 127, batch = rem >> 5, chunk = rem & 31;
        const unsigned short* A = (which ? p.Ga : p.Gd) + (size_t)batch * 524288;
        const unsigned short* B = (which ? p.T  : p.P ) + (size_t)batch * 524288;
        float* out = p.Spart + ((size_t)(which * 4 + batch) * 32 + chunk) * 16384;
        const int kbeg = chunk * 128;

        f32x4 acc[4][4] = {};
        for (int k0 = kbeg; k0 < kbeg + 128; k0 += 32) {
            #pragma unroll
            for (int i = 0; i < 2; ++i) {            // 128x32 bf16 = 512 u16x8 each
                int c = tid + i * 256, row = c >> 2, c8 = c & 3;
                *(u16x8*)&sm.sp.As[row][c8 * 8] = *(const u16x8*)(A + (size_t)row * 4096 + k0 + c8 * 8);
                *(u16x8*)&sm.sp.Bs[row][c8 * 8] = *(const u16x8*)(B + (size_t)row * 4096 + k0 + c8 * 8);
            }
            __syncthreads();
            bf16x8 af[4], bb[4];
            #pragma unroll
            for (int i = 0; i < 4; ++i) af[i] = ldfrag(&sm.sp.As[wr * 64 + i * 16 + ln][q * 8]);
            #pragma unroll
            for (int j = 0; j < 4; ++j) bb[j] = ldfrag(&sm.sp.Bs[wc * 64 + j * 16 + ln][q * 8]);
            #pragma unroll
            for (int i = 0; i < 4; ++i)
                #pragma unroll
                for (int j = 0; j < 4; ++j)
                    acc[i][j] = __builtin_amdgcn_mfma_f32_16x16x32_bf16(af[i], bb[j], acc[i][j], 0, 0, 0);
            __syncthreads();
        }
        #pragma unroll
        for (int i = 0; i < 4; ++i)
            #pragma unroll
            for (int j = 0; j < 4; ++j)
                #pragma unroll
                for (int r = 0; r < 4; ++r) {
                    int m = wr * 64 + i * 16 + q * 4 + r, n = wc * 64 + j * 16 + ln;
                    out[m * 128 + n] = acc[i][j][r];
                }
    }
    grid.sync();

    // ---------------- P2b: reduce the 32 split-K partials --------------------
    {
        const int idx = bx * 256 + tid;            // 512*256 = 131072 outputs
        const int c = idx >> 14, e = idx & 16383;
        float s = 0.f;
        #pragma unroll
        for (int k = 0; k < 32; ++k) s += p.Spart[((size_t)(c * 32 + k) << 14) + e];
        p.S[idx] = s;
    }
    grid.sync();

    // ---------------- P3: NA/ND = S @ X_v / 4096 (128x64 tile, 2 K-halves) ---
    {
        const int wb = bx >> 6, which = wb >> 2, batch = wb & 3;
        const int j0 = (bx & 63) * 64;
        const float* Sm = p.S + (size_t)(which * 4 + batch) * 16384;
        const unsigned short* Bsrc = (which ? p.P : p.T) + (size_t)batch * 524288;
        unsigned short* O = (which ? p.ND : p.NA) + (size_t)batch * 524288;

        f32x4 acc[4][2] = {};
        for (int h = 0; h < 2; ++h) {
            const int k0 = h * 64;
            #pragma unroll
            for (int i = 0; i < 8; ++i) {            // S half: 128x64 fp32 -> bf16
                int c = tid + i * 256, row = c >> 4, c4 = c & 15;
                float4 v = *((const float4*)(Sm + (size_t)row * 128 + k0) + c4);
                u16x4 pk; pk[0]=f2bf(v.x); pk[1]=f2bf(v.y); pk[2]=f2bf(v.z); pk[3]=f2bf(v.w);
                *(u16x4*)&sm.nd.As[row][c4 * 4] = pk;
            }
            #pragma unroll
            for (int i = 0; i < 2; ++i) {            // X_v[k0+k][j0..j0+63] -> Bs[j][k]
                int c = tid + i * 256, k = c >> 3, jj0 = (c & 7) * 8;
                u16x8 v = *(const u16x8*)(Bsrc + (size_t)(k0 + k) * 4096 + j0 + jj0);
                #pragma unroll
                for (int jj = 0; jj < 8; ++jj) sm.nd.Bs[jj0 + jj][k] = v[jj];
            }
            __syncthreads();
            #pragma unroll
            for (int ks = 0; ks < 2; ++ks) {
                bf16x8 af[4], bb[2];
                #pragma unroll
                for (int i = 0; i < 4; ++i) af[i] = ldfrag(&sm.nd.As[wr * 64 + i * 16 + ln][ks * 32 + q * 8]);
                #pragma unroll
                for (int j = 0; j < 2; ++j) bb[j] = ldfrag(&sm.nd.Bs[wc * 32 + j * 16 + ln][ks * 32 + q * 8]);
                #pragma unroll
                for (int i = 0; i < 4; ++i)
                    #pragma unroll
                    for (int j = 0; j < 2; ++j)
                        acc[i][j] = __builtin_amdgcn_mfma_f32_16x16x32_bf16(af[i], bb[j], acc[i][j], 0, 0, 0);
            }
            __syncthreads();
        }
        #pragma unroll
        for (int i = 0; i < 4; ++i)
            #pragma unroll
            for (int j = 0; j < 2; ++j)
                #pragma unroll
                for (int r = 0; r < 4; ++r) {
                    int m = wr * 64 + i * 16 + q * 4 + r;
                    int jj = j0 + wc * 32 + j * 16 + ln;
                    O[(size_t)m * 4096 + jj] = f2bf(acc[i][j][r] * (1.0f / 4096.0f));
                }
    }
    grid.sync();

    // ---------------- P4: final linears + bias + residual (64x128 tile) ------
    {
        const int z = bx >> 8;
        const int n0 = (bx & 1) * 128, m0 = ((bx >> 1) & 127) * 64;
        const unsigned short* A = z ? p.ND : p.NA;
        const unsigned short* Wm = p.Wbf + (size_t)(z ? 5 : 4) * 65536;
        const float* Bv = z ? p.Q_b : p.W_b;
        const float* R  = z ? p.detect : p.aim;
        float* O = z ? p.out_det : p.out_aim;

        f32x4 acc[2][4] = {};
        for (int k0 = 0; k0 < 256; k0 += 32) {
            {
                int row = tid >> 2, c8 = tid & 3;
                *(u16x8*)&sm.fin.As[row][c8 * 8] =
                    *(const u16x8*)(A + (size_t)(m0 + row) * 256 + k0 + c8 * 8);
            }
            #pragma unroll
            for (int i = 0; i < 2; ++i) {
                int c = tid + i * 256, row = c >> 2, c8 = c & 3;
                *(u16x8*)&sm.fin.Bs[row][c8 * 8] =
                    *(const u16x8*)(Wm + (size_t)(n0 + row) * 256 + k0 + c8 * 8);
            }
            __syncthreads();
            bf16x8 af[2], bb[4];
            #pragma unroll
            for (int i = 0; i < 2; ++i) af[i] = ldfrag(&sm.fin.As[wr * 32 + i * 16 + ln][q * 8]);
            #pragma unroll
            for (int j = 0; j < 4; ++j) bb[j] = ldfrag(&sm.fin.Bs[wc * 64 + j * 16 + ln][q * 8]);
            #pragma unroll
            for (int i = 0; i < 2; ++i)
                #pragma unroll
                for (int j = 0; j < 4; ++j)
                    acc[i][j] = __builtin_amdgcn_mfma_f32_16x16x32_bf16(af[i], bb[j], acc[i][j], 0, 0, 0);
            __syncthreads();
        }
        #pragma unroll
        for (int i = 0; i < 2; ++i)
            #pragma unroll
            for (int j = 0; j < 4; ++j) {
                int n = n0 + wc * 64 + j * 16 + ln;
                float bias = Bv[n];
                #pragma unroll
                for (int r = 0; r < 4; ++r) {
                    int m = m0 + wr * 32 + i * 16 + q * 4 + r;
                    O[(size_t)m * 256 + n] = acc[i][j][r] + bias + R[(size_t)m * 256 + n];
                }
            }
    }
}

// ======================= fallback: round-3 kernels ===========================
__global__ __launch_bounds__(256)
void prep_kernel(Params p)
{
    const int z = blockIdx.y;
    const float* src; size_t n4; unsigned short* o;
    switch (z) {
        case 0: src = p.g_w;    n4 = 16384;  o = p.Wbf;             break;
        case 1: src = p.g2_w;   n4 = 16384;  o = p.Wbf + 65536;     break;
        case 2: src = p.th_w;   n4 = 16384;  o = p.Wbf + 2*65536;   break;
        case 3: src = p.ph_w;   n4 = 16384;  o = p.Wbf + 3*65536;   break;
        case 4: src = p.W_w;    n4 = 16384;  o = p.Wbf + 4*65536;   break;
        case 5: src = p.Q_w;    n4 = 16384;  o = p.Wbf + 5*65536;   break;
        case 6: src = p.aim;    n4 = 524288; o = p.Abf;             break;
        default:src = p.detect; n4 = 524288; o = p.Dbf;             break;
    }
    const size_t stride = (size_t)gridDim.x * 256;
    for (size_t i = blockIdx.x * 256 + threadIdx.x; i < n4; i += stride) {
        float4 v = ((const float4*)src)[i];
        u16x4 pk; pk[0]=f2bf(v.x); pk[1]=f2bf(v.y); pk[2]=f2bf(v.z); pk[3]=f2bf(v.w);
        ((u16x4*)o)[i] = pk;
    }
}

__global__ __launch_bounds__(256)
void lin4_kernel(Params p)
{
    const int z = blockIdx.z, set = blockIdx.x;
    const unsigned short* A = z ? p.Dbf : p.Abf;
    const int wslot = z ? (set ? 0 : 3) : (set ? 1 : 2);
    const unsigned short* Wm = p.Wbf + (size_t)wslot * 65536;
    const float* Bv = z ? (set ? p.g_b : p.ph_b) : (set ? p.g2_b : p.th_b);
    unsigned short* O = z ? (set ? p.Gd : p.P) : (set ? p.Ga : p.T);
    const int m0 = blockIdx.y * 64;

    __shared__ unsigned short As[64][40];
    __shared__ unsigned short Bs[256][40];
    const int tid = threadIdx.x, lane = tid & 63, w = tid >> 6;
    const int wr = w >> 1, wc = w & 1, q = lane >> 4, ln = lane & 15;

    f32x4 acc[2][8] = {};
    for (int k0 = 0; k0 < 256; k0 += 32) {
        {
            int row = tid >> 2, c8 = tid & 3;
            *(u16x8*)&As[row][c8 * 8] = *(const u16x8*)(A + (size_t)(m0 + row) * 256 + k0 + c8 * 8);
        }
        #pragma unroll
        for (int i = 0; i < 4; ++i) {
            int c = tid + i * 256, row = c >> 2, c8 = c & 3;
            *(u16x8*)&Bs[row][c8 * 8] = *(const u16x8*)(Wm + (size_t)row * 256 + k0 + c8 * 8);
        }
        __syncthreads();
        bf16x8 af[2], bb[8];
        #pragma unroll
        for (int i = 0; i < 2; ++i) af[i] = ldfrag(&As[wr * 32 + i * 16 + ln][q * 8]);
        #pragma unroll
        for (int j = 0; j < 8; ++j) bb[j] = ldfrag(&Bs[wc * 128 + j * 16 + ln][q * 8]);
        #pragma unroll
        for (int i = 0; i < 2; ++i)
            #pragma unroll
            for (int j = 0; j < 8; ++j)
                acc[i][j] = __builtin_amdgcn_mfma_f32_16x16x32_bf16(af[i], bb[j], acc[i][j], 0, 0, 0);
        __syncthreads();
    }
    #pragma unroll
    for (int i = 0; i < 2; ++i)
        #pragma unroll
        for (int j = 0; j < 8; ++j) {
            int n = wc * 128 + j * 16 + ln;
            float bias = Bv[n];
            #pragma unroll
            for (int r = 0; r < 4; ++r) {
                int m = m0 + wr * 32 + i * 16 + q * 4 + r;
                O[(size_t)m * 256 + n] = f2bf(acc[i][j][r] + bias);
            }
        }
}

__global__ __launch_bounds__(256)
void s_part_kernel(Params p)
{
    const int bz = blockIdx.x;
    const int which = bz >> 7, rem = bz & 127, batch = rem >> 5, chunk = rem & 31;
    const unsigned short* A = (which ? p.Ga : p.Gd) + (size_t)batch * 524288;
    const unsigned short* B = (which ? p.T  : p.P ) + (size_t)batch * 524288;
    float* out = p.Spart + ((size_t)(which * 4 + batch) * 32 + chunk) * 16384;
    const int kbeg = chunk * 128;

    __shared__ unsigned short As[128][72], Bs[128][72];
    const int tid = threadIdx.x, lane = tid & 63, w = tid >> 6;
    const int wr = w >> 1, wc = w & 1, q = lane >> 4, ln = lane & 15;

    f32x4 acc[4][4] = {};
    for (int kk = 0; kk < 2; ++kk) {
        const int k0 = kbeg + kk * 64;
        #pragma unroll
        for (int i = 0; i < 4; ++i) {
            int c = tid + i * 256, row = c >> 3, c8 = c & 7;
            *(u16x8*)&As[row][c8 * 8] = *(const u16x8*)(A + (size_t)row * 4096 + k0 + c8 * 8);
            *(u16x8*)&Bs[row][c8 * 8] = *(const u16x8*)(B + (size_t)row * 4096 + k0 + c8 * 8);
        }
        __syncthreads();
        #pragma unroll
        for (int ks = 0; ks < 2; ++ks) {
            bf16x8 af[4], bb[4];
            #pragma unroll
            for (int i = 0; i < 4; ++i) af[i] = ldfrag(&As[wr * 64 + i * 16 + ln][ks * 32 + q * 8]);
            #pragma unroll
            for (int j = 0; j < 4; ++j) bb[j] = ldfrag(&Bs[wc * 64 + j * 16 + ln][ks * 32 + q * 8]);
            #pragma unroll
            for (int i = 0; i < 4; ++i)
                #pragma unroll
                for (int j = 0; j < 4; ++j)
                    acc[i][j] = __builtin_amdgcn_mfma_f32_16x16x32_bf16(af[i], bb[j], acc[i][j], 0, 0, 0);
        }
        __syncthreads();
    }
    #pragma unroll
    for (int i = 0; i < 4; ++i)
        #pragma unroll
        for (int j = 0; j < 4; ++j)
            #pragma unroll
            for (int r = 0; r < 4; ++r) {
                int m = wr * 64 + i * 16 + q * 4 + r, n = wc * 64 + j * 16 + ln;
                out[m * 128 + n] = acc[i][j][r];
            }
}

__global__ __launch_bounds__(256)
void sred_kernel(Params p)
{
    const int idx = blockIdx.x * 256 + threadIdx.x;
    const int c = idx >> 14, e = idx & 16383;
    float s = 0.f;
    #pragma unroll
    for (int k = 0; k < 32; ++k) s += p.Spart[((size_t)(c * 32 + k) << 14) + e];
    p.S[idx] = s;
}

__global__ __launch_bounds__(256)
void nand_kernel(Params p)
{
    const int which = blockIdx.z >> 2, batch = blockIdx.z & 3;
    const float* Sm = p.S + (size_t)(which * 4 + batch) * 16384;
    const unsigned short* Bsrc = (which ? p.P : p.T) + (size_t)batch * 524288;
    unsigned short* O = (which ? p.ND : p.NA) + (size_t)batch * 524288;
    const int j0 = blockIdx.x * 64;

    __shared__ unsigned short As[128][136];
    __shared__ unsigned short Bs[64][136];
    const int tid = threadIdx.x, lane = tid & 63, w = tid >> 6;
    const int wr = w >> 1, wc = w & 1, q = lane >> 4, ln = lane & 15;

    #pragma unroll
    for (int i = 0; i < 16; ++i) {
        int c = tid + i * 256, row = c >> 5, c4 = c & 31;
        float4 v = *((const float4*)(Sm + (size_t)row * 128) + c4);
        u16x4 pk; pk[0]=f2bf(v.x); pk[1]=f2bf(v.y); pk[2]=f2bf(v.z); pk[3]=f2bf(v.w);
        *(u16x4*)&As[row][c4 * 4] = pk;
    }
    #pragma unroll
    for (int i = 0; i < 4; ++i) {
        int c = tid + i * 256, k = c >> 3, jj0 = (c & 7) * 8;
        u16x8 v = *(const u16x8*)(Bsrc + (size_t)k * 4096 + j0 + jj0);
        #pragma unroll
        for (int jj = 0; jj < 8; ++jj) Bs[jj0 + jj][k] = v[jj];
    }
    __syncthreads();

    f32x4 acc[4][2] = {};
    #pragma unroll
    for (int ks = 0; ks < 4; ++ks) {
        bf16x8 af[4], bb[2];
        #pragma unroll
        for (int i = 0; i < 4; ++i) af[i] = ldfrag(&As[wr * 64 + i * 16 + ln][ks * 32 + q * 8]);
        #pragma unroll
        for (int j = 0; j < 2; ++j) bb[j] = ldfrag(&Bs[wc * 32 + j * 16 + ln][ks * 32 + q * 8]);
        #pragma unroll
        for (int i = 0; i < 4; ++i)
            #pragma unroll
            for (int j = 0; j < 2; ++j)
                acc[i][j] = __builtin_amdgcn_mfma_f32_16x16x32_bf16(af[i], bb[j], acc[i][j], 0, 0, 0);
    }
    #pragma unroll
    for (int i = 0; i < 4; ++i)
        #pragma unroll
        for (int j = 0; j < 2; ++j)
            #pragma unroll
            for (int r = 0; r < 4; ++r) {
                int m = wr * 64 + i * 16 + q * 4 + r;
                int jj = j0 + wc * 32 + j * 16 + ln;
                O[(size_t)m * 4096 + jj] = f2bf(acc[i][j][r] * (1.0f / 4096.0f));
            }
}

__global__ __launch_bounds__(256)
void final_kernel(Params p)
{
    const int z = blockIdx.z;
    const unsigned short* A = z ? p.ND : p.NA;
    const unsigned short* Wm = p.Wbf + (size_t)(z ? 5 : 4) * 65536;
    const float* Bv = z ? p.Q_b : p.W_b;
    const float* R  = z ? p.detect : p.aim;
    float* O = z ? p.out_det : p.out_aim;
    const int m0 = blockIdx.y * 64, n0 = blockIdx.x * 128;

    __shared__ unsigned short As[64][40], Bs[128][40];
    const int tid = threadIdx.x, lane = tid & 63, w = tid >> 6;
    const int wr = w >> 1, wc = w & 1, q = lane >> 4, ln = lane & 15;

    f32x4 acc[2][4] = {};
    for (int k0 = 0; k0 < 256; k0 += 32) {
        {
            int row = tid >> 2, c8 = tid & 3;
            *(u16x8*)&As[row][c8 * 8] = *(const u16x8*)(A + (size_t)(m0 + row) * 256 + k0 + c8 * 8);
        }
        #pragma unroll
        for (int i = 0; i < 2; ++i) {
            int c = tid + i * 256, row = c >> 2, c8 = c & 3;
            *(u16x8*)&Bs[row][c8 * 8] = *(const u16x8*)(Wm + (size_t)(n0 + row) * 256 + k0 + c8 * 8);
        }
        __syncthreads();
        bf16x8 af[2], bb[4];
        #pragma unroll
        for (int i = 0; i < 2; ++i) af[i] = ldfrag(&As[wr * 32 + i * 16 + ln][q * 8]);
        #pragma unroll
        for (int j = 0; j < 4; ++j) bb[j] = ldfrag(&Bs[wc * 64 + j * 16 + ln][q * 8]);
        #pragma unroll
        for (int i = 0; i < 2; ++i)
            #pragma unroll
            for (int j = 0; j < 4; ++j)
                acc[i][j] = __builtin_amdgcn_mfma_f32_16x16x32_bf16(af[i], bb[j], acc[i][j], 0, 0, 0);
        __syncthreads();
    }
    #pragma unroll
    for (int i = 0; i < 2; ++i)
        #pragma unroll
        for (int j = 0; j < 4; ++j) {
            int n = n0 + wc * 64 + j * 16 + ln;
            float bias = Bv[n];
            #pragma unroll
            for (int r = 0; r < 4; ++r) {
                int m = m0 + wr * 32 + i * 16 + q * 4 + r;
                O[(size_t)m * 256 + n] = acc[i][j][r] + bias + R[(size_t)m * 256 + n];
            }
        }
}

extern "C" void kernel_launch(void* const* d_in, const int* in_sizes, int n_in,
                              void* d_out, int out_size, void* d_ws, size_t ws_size,
                              hipStream_t stream)
{
    Params p;
    p.detect = (const float*)d_in[0];
    p.aim    = (const float*)d_in[1];
    p.g_w  = (const float*)d_in[2];  p.g_b  = (const float*)d_in[3];
    p.g2_w = (const float*)d_in[4];  p.g2_b = (const float*)d_in[5];
    p.th_w = (const float*)d_in[6];  p.th_b = (const float*)d_in[7];
    p.ph_w = (const float*)d_in[8];  p.ph_b = (const float*)d_in[9];
    p.W_w  = (const float*)d_in[10]; p.W_b  = (const float*)d_in[11];
    p.Q_w  = (const float*)d_in[12]; p.Q_b  = (const float*)d_in[13];

    const size_t TOT = 8192L * 256;

    unsigned short* ws16 = (unsigned short*)d_ws;
    p.Wbf = ws16;                    // [6][65536]: g,g2,th,ph,W,Q
    p.Abf = p.Wbf + 6 * 65536;
    p.Dbf = p.Abf + TOT;
    p.T   = p.Dbf + TOT;
    p.P   = p.T  + TOT;
    p.Gd  = p.P  + TOT;
    p.Ga  = p.Gd + TOT;
    p.NA  = p.Ga + TOT;
    p.ND  = p.NA + TOT;
    p.S     = (float*)(p.ND + TOT);          // [2][4][128][128]
    p.Spart = p.S + 2 * 4 * 16384;           // [2][4][32][128][128]

    p.out_det = (float*)d_out;
    p.out_aim = p.out_det + TOT;

    void* args[] = { &p };
    hipError_t e = hipLaunchCooperativeKernel((const void*)mega_kernel, dim3(512),
                                              dim3(256), args, 0, stream);
    if (e != hipSuccess) {
        // fallback: proven round-3 multi-kernel path
        prep_kernel<<<dim3(256, 8), 256, 0, stream>>>(p);
        lin4_kernel<<<dim3(2, 128, 2), 256, 0, stream>>>(p);
        s_part_kernel<<<dim3(256), 256, 0, stream>>>(p);
        sred_kernel<<<dim3(512), 256, 0, stream>>>(p);
        nand_kernel<<<dim3(64, 1, 8), 256, 0, stream>>>(p);
        final_kernel<<<dim3(2, 128, 2), 256, 0, stream>>>(p);
    }
}

// Round 6
// 179.436 us; speedup vs baseline: 2.6062x; 2.6062x over previous
//
#include <hip/hip_runtime.h>

// B=4, N=2048, C=256, ic=128.  Algebra (validated rounds 1-3):
//   T=lin(aim,theta) P=lin(detect,phi) Gd=lin(detect,g) Ga=lin(aim,g2)   [bf16]
//   X_v := per-batch view [128,4096] of [2048,256] (pure reshape)
//   S_aT = Gd_v @ P_v^T ; S_bT = Ga_v @ T_v^T        [128,128] fp32
//   NA_v = S_aT @ T_v /4096 ; ND_v = S_bT @ P_v /4096
//   out_aim = lin(NA,W)+aim ; out_det = lin(ND,Q)+detect  (order: det,aim)
// Round 6: cooperative grid.sync measured ~60us each -> abandoned. Back to
// stream-ordered kernels but consolidated 6->4 dispatches:
//   memset(S) ; linall (fp32-in, prep fused) ; s_atomic (split-K atomicAdd,
//   kills Spart+sred) ; outfused (nand+final chained in-LDS, kills NA/ND).
// Fusion key: j-strip of 256 in the [128,4096] view = complete rows of the
// [2048,256] tensor (row = m*16 + strip, col = j&255), so GEMM1's output tile
// is a valid K=256 A-operand for the final linear without touching HBM.

typedef __attribute__((ext_vector_type(4))) float  f32x4;
typedef __attribute__((ext_vector_type(8))) __bf16 bf16x8;
typedef __attribute__((ext_vector_type(8))) unsigned short u16x8;
typedef __attribute__((ext_vector_type(4))) unsigned short u16x4;

__device__ inline unsigned short f2bf(float f) {
    union { float f; unsigned u; } c; c.f = f;
    unsigned r = c.u + 0x7FFF + ((c.u >> 16) & 1);   // RNE
    return (unsigned short)(r >> 16);
}
__device__ inline bf16x8 ldfrag(const unsigned short* p) {
    return __builtin_bit_cast(bf16x8, *(const u16x8*)p);
}

struct Params {
    const float *detect, *aim;
    const float *g_w, *g2_w, *th_w, *ph_w, *W_w, *Q_w;
    const float *g_b, *g2_b, *th_b, *ph_b, *W_b, *Q_b;
    unsigned short *Wbf;                 // [2][65536] bf16: W, Q
    unsigned short *T, *P, *Gd, *Ga;     // [4][2048][256] bf16 each
    float *S;                            // [2][4][128][128] fp32 (atomic acc)
    float *out_det, *out_aim;
};

// ---------------- K1: four input linears, fp32 in, bf16 out ------------------
// grid (2,128,2): x=set, y=m-tile(64), z=input(0:aim,1:detect). Tile 64x256, BK=32.
__global__ __launch_bounds__(256)
void linall_kernel(Params p)
{
    const int z = blockIdx.z, set = blockIdx.x;
    const float* A  = z ? p.detect : p.aim;
    const float* Wm = z ? (set ? p.g_w : p.ph_w) : (set ? p.g2_w : p.th_w);
    const float* Bv = z ? (set ? p.g_b : p.ph_b) : (set ? p.g2_b : p.th_b);
    unsigned short* O = z ? (set ? p.Gd : p.P) : (set ? p.Ga : p.T);
    const int m0 = blockIdx.y * 64;

    __shared__ unsigned short As[64][40];    // [m][k] bf16
    __shared__ unsigned short Bs[256][40];   // [n][k] bf16

    const int tid = threadIdx.x, lane = tid & 63, w = tid >> 6;
    const int wr = w >> 1, wc = w & 1, q = lane >> 4, ln = lane & 15;

    f32x4 acc[2][8] = {};

    for (int k0 = 0; k0 < 256; k0 += 32) {
        #pragma unroll
        for (int i = 0; i < 2; ++i) {            // A: 64x32 fp32 = 512 float4
            int c = tid + i * 256, row = c >> 3, c4 = c & 7;
            float4 v = *((const float4*)(A + (size_t)(m0 + row) * 256 + k0) + c4);
            u16x4 pk; pk[0]=f2bf(v.x); pk[1]=f2bf(v.y); pk[2]=f2bf(v.z); pk[3]=f2bf(v.w);
            *(u16x4*)&As[row][c4 * 4] = pk;
        }
        #pragma unroll
        for (int i = 0; i < 8; ++i) {            // W: 256x32 fp32 = 2048 float4
            int c = tid + i * 256, row = c >> 3, c4 = c & 7;
            float4 v = *((const float4*)(Wm + (size_t)row * 256 + k0) + c4);
            u16x4 pk; pk[0]=f2bf(v.x); pk[1]=f2bf(v.y); pk[2]=f2bf(v.z); pk[3]=f2bf(v.w);
            *(u16x4*)&Bs[row][c4 * 4] = pk;
        }
        __syncthreads();
        bf16x8 af[2], bb[8];
        #pragma unroll
        for (int i = 0; i < 2; ++i) af[i] = ldfrag(&As[wr * 32 + i * 16 + ln][q * 8]);
        #pragma unroll
        for (int j = 0; j < 8; ++j) bb[j] = ldfrag(&Bs[wc * 128 + j * 16 + ln][q * 8]);
        #pragma unroll
        for (int i = 0; i < 2; ++i)
            #pragma unroll
            for (int j = 0; j < 8; ++j)
                acc[i][j] = __builtin_amdgcn_mfma_f32_16x16x32_bf16(af[i], bb[j], acc[i][j], 0, 0, 0);
        __syncthreads();
    }

    #pragma unroll
    for (int i = 0; i < 2; ++i)
        #pragma unroll
        for (int j = 0; j < 8; ++j) {
            int n = wc * 128 + j * 16 + ln;
            float bias = Bv[n];
            #pragma unroll
            for (int r = 0; r < 4; ++r) {
                int m = m0 + wr * 32 + i * 16 + q * 4 + r;
                O[(size_t)m * 256 + n] = f2bf(acc[i][j][r] + bias);
            }
        }
}

// ---------------- K2: S via split-K + fp32 atomicAdd; also W/Q -> bf16 -------
// grid (256): bx = which*128 + batch*32 + chunk (KC=128, BK=64). Tile 128x128.
// S must be zeroed (memsetAsync) before this kernel.
__global__ __launch_bounds__(256)
void s_atomic_kernel(Params p)
{
    const int bx = blockIdx.x, tid = threadIdx.x;

    // side job: convert W_w,Q_w (2 x 65536 fp32) to Wbf; 128 float4 per block
    if (tid < 128) {
        int fi = bx * 128 + tid;                    // float4 index, 32768 total
        const float* src = fi < 16384 ? p.W_w : p.Q_w;
        int li = fi & 16383;
        float4 v = ((const float4*)src)[li];
        u16x4 pk; pk[0]=f2bf(v.x); pk[1]=f2bf(v.y); pk[2]=f2bf(v.z); pk[3]=f2bf(v.w);
        ((u16x4*)p.Wbf)[fi] = pk;
    }

    const int which = bx >> 7, rem = bx & 127, batch = rem >> 5, chunk = rem & 31;
    const unsigned short* A = (which ? p.Ga : p.Gd) + (size_t)batch * 524288;
    const unsigned short* B = (which ? p.T  : p.P ) + (size_t)batch * 524288;
    float* Sout = p.S + (size_t)(which * 4 + batch) * 16384;
    const int kbeg = chunk * 128;

    __shared__ unsigned short As[128][72], Bs[128][72];
    const int lane = tid & 63, w = tid >> 6;
    const int wr = w >> 1, wc = w & 1, q = lane >> 4, ln = lane & 15;

    f32x4 acc[4][4] = {};

    for (int kk = 0; kk < 2; ++kk) {
        const int k0 = kbeg + kk * 64;
        #pragma unroll
        for (int i = 0; i < 4; ++i) {            // 128x64 bf16 = 1024 u16x8 each
            int c = tid + i * 256, row = c >> 3, c8 = c & 7;
            *(u16x8*)&As[row][c8 * 8] = *(const u16x8*)(A + (size_t)row * 4096 + k0 + c8 * 8);
            *(u16x8*)&Bs[row][c8 * 8] = *(const u16x8*)(B + (size_t)row * 4096 + k0 + c8 * 8);
        }
        __syncthreads();
        #pragma unroll
        for (int ks = 0; ks < 2; ++ks) {
            bf16x8 af[4], bb[4];
            #pragma unroll
            for (int i = 0; i < 4; ++i) af[i] = ldfrag(&As[wr * 64 + i * 16 + ln][ks * 32 + q * 8]);
            #pragma unroll
            for (int j = 0; j < 4; ++j) bb[j] = ldfrag(&Bs[wc * 64 + j * 16 + ln][ks * 32 + q * 8]);
            #pragma unroll
            for (int i = 0; i < 4; ++i)
                #pragma unroll
                for (int j = 0; j < 4; ++j)
                    acc[i][j] = __builtin_amdgcn_mfma_f32_16x16x32_bf16(af[i], bb[j], acc[i][j], 0, 0, 0);
        }
        __syncthreads();
    }

    #pragma unroll
    for (int i = 0; i < 4; ++i)
        #pragma unroll
        for (int j = 0; j < 4; ++j)
            #pragma unroll
            for (int r = 0; r < 4; ++r) {
                int m = wr * 64 + i * 16 + q * 4 + r, n = wc * 64 + j * 16 + ln;
                atomicAdd(&Sout[m * 128 + n], acc[i][j][r]);
            }
}

// ---------------- K3: fused (S @ X_v /4096) -> final linear -> d_out ---------
// grid (512): bx = which*256 + batch*64 + strip*4 + mq.
// GEMM1: NAb[32 x 256] = S[m0..m0+32][0..128] @ X_v[0..128][s*256..+256] /4096
// GEMM2: Out rows (m*16+s) = NAb @ W^T + bias + residual   (K=256, in-LDS chain)
__global__ __launch_bounds__(256)
void outfused_kernel(Params p)
{
    const int bx = blockIdx.x, tid = threadIdx.x;
    const int lane = tid & 63, w = tid >> 6;
    const int wr = w >> 1, wc = w & 1, q = lane >> 4, ln = lane & 15;

    const int which = bx >> 8, batch = (bx >> 6) & 3, s = (bx >> 2) & 15, mq = bx & 3;
    const int m0 = mq * 32;
    const float* Sm = p.S + (size_t)(which * 4 + batch) * 16384;
    const unsigned short* X = (which ? p.P : p.T) + (size_t)batch * 524288;
    const unsigned short* Wm = p.Wbf + (which ? 65536 : 0);
    const float* Bv = which ? p.Q_b : p.W_b;
    const float* R  = which ? p.detect : p.aim;
    float* O = which ? p.out_det : p.out_aim;

    __shared__ union {
        struct { unsigned short Ss[32][40];  unsigned short Xs[256][40]; } g1;  // 22.5 KB
        struct { unsigned short NAs[32][264]; unsigned short Ws[256][40]; } g2; // 37.0 KB
    } sm;

    // ---- GEMM1: rows m0+wr*16+ln, cols wc*128 + nt*16 + ln, K=128 in 4 chunks
    f32x4 acc1[8] = {};
    for (int kc = 0; kc < 4; ++kc) {
        const int k0 = kc * 32;
        {                                        // S tile 32x32 fp32 -> bf16
            int row = tid >> 3, c4 = tid & 7;
            float4 v = *((const float4*)(Sm + (size_t)(m0 + row) * 128 + k0) + c4);
            u16x4 pk; pk[0]=f2bf(v.x); pk[1]=f2bf(v.y); pk[2]=f2bf(v.z); pk[3]=f2bf(v.w);
            *(u16x4*)&sm.g1.Ss[row][c4 * 4] = pk;
        }
        #pragma unroll
        for (int i = 0; i < 4; ++i) {            // X strip transpose: [k][j] -> Xs[j][k]
            int c = tid + i * 256, k = c >> 5, j8 = (c & 31) * 8;
            u16x8 v = *(const u16x8*)(X + (size_t)(k0 + k) * 4096 + s * 256 + j8);
            #pragma unroll
            for (int jj = 0; jj < 8; ++jj) sm.g1.Xs[j8 + jj][k] = v[jj];
        }
        __syncthreads();
        bf16x8 af = ldfrag(&sm.g1.Ss[wr * 16 + ln][q * 8]);
        #pragma unroll
        for (int nt = 0; nt < 8; ++nt) {
            bf16x8 bb = ldfrag(&sm.g1.Xs[wc * 128 + nt * 16 + ln][q * 8]);
            acc1[nt] = __builtin_amdgcn_mfma_f32_16x16x32_bf16(af, bb, acc1[nt], 0, 0, 0);
        }
        __syncthreads();
    }

    // ---- stash NAb (scaled, bf16) into LDS as GEMM2's A operand
    #pragma unroll
    for (int nt = 0; nt < 8; ++nt)
        #pragma unroll
        for (int r = 0; r < 4; ++r) {
            int mi = wr * 16 + q * 4 + r;
            int jj = wc * 128 + nt * 16 + ln;
            sm.g2.NAs[mi][jj] = f2bf(acc1[nt][r] * (1.0f / 4096.0f));
        }
    __syncthreads();

    // ---- GEMM2: Out[32 x 256] = NAs @ Wm^T, K=256 in 8 chunks
    f32x4 acc2[8] = {};
    for (int cc = 0; cc < 8; ++cc) {
        const int c0 = cc * 32;
        #pragma unroll
        for (int i = 0; i < 4; ++i) {            // W tile 256x32 bf16
            int c = tid + i * 256, row = c >> 2, c8 = c & 3;
            *(u16x8*)&sm.g2.Ws[row][c8 * 8] = *(const u16x8*)(Wm + (size_t)row * 256 + c0 + c8 * 8);
        }
        __syncthreads();
        bf16x8 af = ldfrag(&sm.g2.NAs[wr * 16 + ln][c0 + q * 8]);
        #pragma unroll
        for (int nt = 0; nt < 8; ++nt) {
            bf16x8 bb = ldfrag(&sm.g2.Ws[wc * 128 + nt * 16 + ln][q * 8]);
            acc2[nt] = __builtin_amdgcn_mfma_f32_16x16x32_bf16(af, bb, acc2[nt], 0, 0, 0);
        }
        __syncthreads();
    }

    // ---- epilogue: bias + residual, write fp32 output
    #pragma unroll
    for (int nt = 0; nt < 8; ++nt) {
        int n = wc * 128 + nt * 16 + ln;
        float bias = Bv[n];
        #pragma unroll
        for (int r = 0; r < 4; ++r) {
            int mi = wr * 16 + q * 4 + r;                 // [0,32)
            int row = (m0 + mi) * 16 + s;                 // [0,2048) within batch
            size_t idx = ((size_t)batch * 2048 + row) * 256 + n;
            O[idx] = acc2[nt][r] + bias + R[idx];
        }
    }
}

extern "C" void kernel_launch(void* const* d_in, const int* in_sizes, int n_in,
                              void* d_out, int out_size, void* d_ws, size_t ws_size,
                              hipStream_t stream)
{
    Params p;
    p.detect = (const float*)d_in[0];
    p.aim    = (const float*)d_in[1];
    p.g_w  = (const float*)d_in[2];  p.g_b  = (const float*)d_in[3];
    p.g2_w = (const float*)d_in[4];  p.g2_b = (const float*)d_in[5];
    p.th_w = (const float*)d_in[6];  p.th_b = (const float*)d_in[7];
    p.ph_w = (const float*)d_in[8];  p.ph_b = (const float*)d_in[9];
    p.W_w  = (const float*)d_in[10]; p.W_b  = (const float*)d_in[11];
    p.Q_w  = (const float*)d_in[12]; p.Q_b  = (const float*)d_in[13];

    const size_t TOT = 8192L * 256;   // 2,097,152 elems per tensor

    unsigned short* ws16 = (unsigned short*)d_ws;
    p.Wbf = ws16;                    // [2][65536] bf16: W, Q
    p.T   = p.Wbf + 2 * 65536;
    p.P   = p.T  + TOT;
    p.Gd  = p.P  + TOT;
    p.Ga  = p.Gd + TOT;
    p.S   = (float*)(p.Ga + TOT);    // [2][4][128][128] fp32

    p.out_det = (float*)d_out;
    p.out_aim = p.out_det + TOT;

    hipMemsetAsync(p.S, 0, 2 * 4 * 16384 * sizeof(float), stream);
    linall_kernel<<<dim3(2, 128, 2), 256, 0, stream>>>(p);
    s_atomic_kernel<<<dim3(256), 256, 0, stream>>>(p);
    outfused_kernel<<<dim3(512), 256, 0, stream>>>(p);
}

// Round 7
// 161.291 us; speedup vs baseline: 2.8994x; 1.1125x over previous
//
#include <hip/hip_runtime.h>

// B=4, N=2048, C=256, ic=128.  Algebra (validated rounds 1-6):
//   T=lin(aim,theta) P=lin(detect,phi) Gd=lin(detect,g) Ga=lin(aim,g2)   [bf16]
//   X_v := per-batch view [128,4096] of [2048,256] (pure reshape)
//   S_aT = Gd_v @ P_v^T ; S_bT = Ga_v @ T_v^T        [128,128] fp32
//   NA_v = S_aT @ T_v /4096 ; ND_v = S_bT @ P_v /4096
//   out_aim = lin(NA,W)+aim ; out_det = lin(ND,Q)+detect  (order: det,aim)
// Round 7: R6 counters showed outfused burned ~29us/CU in LDS bank conflicts
// (32-way on the scalar X-transpose writes, stride 40 rows: lane*160 mod 32 = 0).
// Fixes: (a) X staged in natural [k][j] layout (stride 268 = 134 banks = 6 mod 32;
// vectorized writes, scalar gather reads <=4-way), (b) split-K via deterministic
// Spart + reduction fused into outfused preamble (atomics & memset & sred gone),
// (c) NAs handoff stride 268 scalar (conflict-free writes), (d) linall 128x256 tile.

typedef __attribute__((ext_vector_type(4))) float  f32x4;
typedef __attribute__((ext_vector_type(8))) __bf16 bf16x8;
typedef __attribute__((ext_vector_type(8))) unsigned short u16x8;
typedef __attribute__((ext_vector_type(4))) unsigned short u16x4;

__device__ inline unsigned short f2bf(float f) {
    union { float f; unsigned u; } c; c.f = f;
    unsigned r = c.u + 0x7FFF + ((c.u >> 16) & 1);   // RNE
    return (unsigned short)(r >> 16);
}
__device__ inline bf16x8 ldfrag(const unsigned short* p) {
    return __builtin_bit_cast(bf16x8, *(const u16x8*)p);
}

struct Params {
    const float *detect, *aim;
    const float *g_w, *g2_w, *th_w, *ph_w, *W_w, *Q_w;
    const float *g_b, *g2_b, *th_b, *ph_b, *W_b, *Q_b;
    unsigned short *Wbf;                 // [2][65536] bf16: W, Q
    unsigned short *T, *P, *Gd, *Ga;     // [4][2048][256] bf16 each
    float *Spart;                        // [2][4][16][128][128] fp32 partials
    float *out_det, *out_aim;
};

// ---------------- K1: four input linears, fp32 in, bf16 out ------------------
// grid (2,64,2): x=set, y=m-tile(128), z=input(0:aim,1:detect). Tile 128x256, BK=32.
__global__ __launch_bounds__(256)
void linall_kernel(Params p)
{
    const int z = blockIdx.z, set = blockIdx.x;
    const float* A  = z ? p.detect : p.aim;
    const float* Wm = z ? (set ? p.g_w : p.ph_w) : (set ? p.g2_w : p.th_w);
    const float* Bv = z ? (set ? p.g_b : p.ph_b) : (set ? p.g2_b : p.th_b);
    unsigned short* O = z ? (set ? p.Gd : p.P) : (set ? p.Ga : p.T);
    const int m0 = blockIdx.y * 128;

    __shared__ unsigned short As[128][40];   // [m][k] bf16
    __shared__ unsigned short Bs[256][40];   // [n][k] bf16

    const int tid = threadIdx.x, lane = tid & 63, w = tid >> 6;
    const int wr = w >> 1, wc = w & 1, q = lane >> 4, ln = lane & 15;

    f32x4 acc[4][8] = {};

    for (int k0 = 0; k0 < 256; k0 += 32) {
        #pragma unroll
        for (int i = 0; i < 4; ++i) {            // A: 128x32 fp32 = 1024 float4
            int c = tid + i * 256, row = c >> 3, c4 = c & 7;
            float4 v = *((const float4*)(A + (size_t)(m0 + row) * 256 + k0) + c4);
            u16x4 pk; pk[0]=f2bf(v.x); pk[1]=f2bf(v.y); pk[2]=f2bf(v.z); pk[3]=f2bf(v.w);
            *(u16x4*)&As[row][c4 * 4] = pk;
        }
        #pragma unroll
        for (int i = 0; i < 8; ++i) {            // W: 256x32 fp32 = 2048 float4
            int c = tid + i * 256, row = c >> 3, c4 = c & 7;
            float4 v = *((const float4*)(Wm + (size_t)row * 256 + k0) + c4);
            u16x4 pk; pk[0]=f2bf(v.x); pk[1]=f2bf(v.y); pk[2]=f2bf(v.z); pk[3]=f2bf(v.w);
            *(u16x4*)&Bs[row][c4 * 4] = pk;
        }
        __syncthreads();
        bf16x8 af[4], bb[8];
        #pragma unroll
        for (int i = 0; i < 4; ++i) af[i] = ldfrag(&As[wr * 64 + i * 16 + ln][q * 8]);
        #pragma unroll
        for (int j = 0; j < 8; ++j) bb[j] = ldfrag(&Bs[wc * 128 + j * 16 + ln][q * 8]);
        #pragma unroll
        for (int i = 0; i < 4; ++i)
            #pragma unroll
            for (int j = 0; j < 8; ++j)
                acc[i][j] = __builtin_amdgcn_mfma_f32_16x16x32_bf16(af[i], bb[j], acc[i][j], 0, 0, 0);
        __syncthreads();
    }

    #pragma unroll
    for (int i = 0; i < 4; ++i)
        #pragma unroll
        for (int j = 0; j < 8; ++j) {
            int n = wc * 128 + j * 16 + ln;
            float bias = Bv[n];
            #pragma unroll
            for (int r = 0; r < 4; ++r) {
                int m = m0 + wr * 64 + i * 16 + q * 4 + r;
                O[(size_t)m * 256 + n] = f2bf(acc[i][j][r] + bias);
            }
        }
}

// ---------------- K2: S partials, deterministic split-K ----------------------
// grid (256): bx = which*128 + batch*32 + ms*16 + chunk. Tile 64(M)x128(N), KC=256.
// Also converts W_w/Q_w -> Wbf (side job).
__global__ __launch_bounds__(256)
void spart_kernel(Params p)
{
    const int bx = blockIdx.x, tid = threadIdx.x;

    if (tid < 128) {                             // W/Q fp32 -> bf16: 128 f4/block
        int fi = bx * 128 + tid;                 // 32768 float4 total
        const float* src = fi < 16384 ? p.W_w : p.Q_w;
        float4 v = ((const float4*)src)[fi & 16383];
        u16x4 pk; pk[0]=f2bf(v.x); pk[1]=f2bf(v.y); pk[2]=f2bf(v.z); pk[3]=f2bf(v.w);
        ((u16x4*)p.Wbf)[fi] = pk;
    }

    const int which = bx >> 7, batch = (bx >> 5) & 3, ms = (bx >> 4) & 1, chunk = bx & 15;
    const unsigned short* A = (which ? p.Ga : p.Gd) + (size_t)batch * 524288;
    const unsigned short* B = (which ? p.T  : p.P ) + (size_t)batch * 524288;
    float* Sp = p.Spart + ((size_t)(which * 4 + batch) * 16 + chunk) * 16384;
    const int kbeg = chunk * 256;

    __shared__ unsigned short As[64][72], Bs[128][72];
    const int lane = tid & 63, w = tid >> 6;
    const int wr = w >> 1, wc = w & 1, q = lane >> 4, ln = lane & 15;

    f32x4 acc[2][4] = {};

    for (int st = 0; st < 4; ++st) {
        const int k0 = kbeg + st * 64;
        #pragma unroll
        for (int i = 0; i < 2; ++i) {            // A: 64x64 bf16 = 512 u16x8
            int c = tid + i * 256, row = c >> 3, c8 = c & 7;
            *(u16x8*)&As[row][c8 * 8] =
                *(const u16x8*)(A + (size_t)(ms * 64 + row) * 4096 + k0 + c8 * 8);
        }
        #pragma unroll
        for (int i = 0; i < 4; ++i) {            // B: 128x64 bf16 = 1024 u16x8
            int c = tid + i * 256, row = c >> 3, c8 = c & 7;
            *(u16x8*)&Bs[row][c8 * 8] = *(const u16x8*)(B + (size_t)row * 4096 + k0 + c8 * 8);
        }
        __syncthreads();
        #pragma unroll
        for (int ks = 0; ks < 2; ++ks) {
            bf16x8 af[2], bb[4];
            #pragma unroll
            for (int i = 0; i < 2; ++i) af[i] = ldfrag(&As[wr * 32 + i * 16 + ln][ks * 32 + q * 8]);
            #pragma unroll
            for (int j = 0; j < 4; ++j) bb[j] = ldfrag(&Bs[wc * 64 + j * 16 + ln][ks * 32 + q * 8]);
            #pragma unroll
            for (int i = 0; i < 2; ++i)
                #pragma unroll
                for (int j = 0; j < 4; ++j)
                    acc[i][j] = __builtin_amdgcn_mfma_f32_16x16x32_bf16(af[i], bb[j], acc[i][j], 0, 0, 0);
        }
        __syncthreads();
    }

    #pragma unroll
    for (int i = 0; i < 2; ++i)
        #pragma unroll
        for (int j = 0; j < 4; ++j)
            #pragma unroll
            for (int r = 0; r < 4; ++r) {
                int m = ms * 64 + wr * 32 + i * 16 + q * 4 + r;
                int n = wc * 64 + j * 16 + ln;
                Sp[m * 128 + n] = acc[i][j][r];
            }
}

// ---------------- K3: fused reduce(Spart) -> GEMM1 -> GEMM2 -> d_out ---------
// grid (512): bx = which*256 + batch*64 + strip*4 + mq.
// pre:   Ss[32x128] = sum_c Spart[g][c][m0..m0+32][:]  (bf16, in LDS)
// GEMM1: NAb[32x256] = Ss @ X_v[:, s*256..+256] / 4096   (Xs natural [k][j])
// GEMM2: Out rows (m*16+s) = NAb @ W^T + bias + residual
__global__ __launch_bounds__(256)
void outfused_kernel(Params p)
{
    const int bx = blockIdx.x, tid = threadIdx.x;
    const int lane = tid & 63, w = tid >> 6;
    const int wr = w >> 1, wc = w & 1, q = lane >> 4, ln = lane & 15;

    const int which = bx >> 8, batch = (bx >> 6) & 3, s = (bx >> 2) & 15, mq = bx & 3;
    const int m0 = mq * 32;
    const float* SpG = p.Spart + ((size_t)(which * 4 + batch) * 16) * 16384;
    const unsigned short* X = (which ? p.P : p.T) + (size_t)batch * 524288;
    const unsigned short* Wm = p.Wbf + (which ? 65536 : 0);
    const float* Bv = which ? p.Q_b : p.W_b;
    const float* R  = which ? p.detect : p.aim;
    float* O = which ? p.out_det : p.out_aim;

    __shared__ union {
        struct { unsigned short Ss[32][136]; unsigned short Xs[32][268]; } g1;  // 25.3 KB
        struct { unsigned short NAs[32][268]; unsigned short Ws[256][40]; } g2; // 36.8 KB
    } sm;

    // ---- preamble: reduce 16 split-K partials into bf16 Ss tile
    #pragma unroll
    for (int it = 0; it < 4; ++it) {
        int fi = tid + it * 256;                 // 1024 float4 tasks (32x128)
        int mi = fi >> 5, k4 = fi & 31;
        const float* base = SpG + (size_t)(m0 + mi) * 128 + k4 * 4;
        f32x4 sum = {};
        #pragma unroll
        for (int c = 0; c < 16; ++c)
            sum += *(const f32x4*)(base + (size_t)c * 16384);
        u16x4 pk; pk[0]=f2bf(sum[0]); pk[1]=f2bf(sum[1]); pk[2]=f2bf(sum[2]); pk[3]=f2bf(sum[3]);
        *(u16x4*)&sm.g1.Ss[mi][k4 * 4] = pk;
    }
    __syncthreads();

    // ---- GEMM1: K=128 in 4 chunks of 32; Xs natural [k][j] layout
    f32x4 acc1[8] = {};
    for (int kc = 0; kc < 4; ++kc) {
        const int k0 = kc * 32;
        #pragma unroll
        for (int i = 0; i < 4; ++i) {            // X: 32k x 256j = 1024 u16x8
            int c = tid + i * 256, kk = c >> 5, j8 = c & 31;
            u16x8 v = *(const u16x8*)(X + (size_t)(k0 + kk) * 4096 + s * 256 + j8 * 8);
            u16x4 lo, hi;
            lo[0]=v[0]; lo[1]=v[1]; lo[2]=v[2]; lo[3]=v[3];
            hi[0]=v[4]; hi[1]=v[5]; hi[2]=v[6]; hi[3]=v[7];
            *(u16x4*)&sm.g1.Xs[kk][j8 * 8]     = lo;
            *(u16x4*)&sm.g1.Xs[kk][j8 * 8 + 4] = hi;
        }
        __syncthreads();
        bf16x8 af = ldfrag(&sm.g1.Ss[wr * 16 + ln][kc * 32 + q * 8]);
        #pragma unroll
        for (int nt = 0; nt < 8; ++nt) {
            int col = wc * 128 + nt * 16 + ln;
            u16x8 t;
            #pragma unroll
            for (int i = 0; i < 8; ++i) t[i] = sm.g1.Xs[q * 8 + i][col];
            acc1[nt] = __builtin_amdgcn_mfma_f32_16x16x32_bf16(
                af, __builtin_bit_cast(bf16x8, t), acc1[nt], 0, 0, 0);
        }
        __syncthreads();
    }

    // ---- handoff: NAb (scaled bf16) into LDS as GEMM2's A operand
    #pragma unroll
    for (int nt = 0; nt < 8; ++nt)
        #pragma unroll
        for (int r = 0; r < 4; ++r) {
            int mi = wr * 16 + q * 4 + r;
            int jj = wc * 128 + nt * 16 + ln;
            sm.g2.NAs[mi][jj] = f2bf(acc1[nt][r] * (1.0f / 4096.0f));
        }
    __syncthreads();

    // ---- GEMM2: Out[32x256] = NAs @ Wm^T, K=256 in 8 chunks
    f32x4 acc2[8] = {};
    for (int cc = 0; cc < 8; ++cc) {
        const int c0 = cc * 32;
        #pragma unroll
        for (int i = 0; i < 4; ++i) {            // W: 256x32 bf16 = 1024 u16x8
            int c = tid + i * 256, row = c >> 2, c8 = c & 3;
            *(u16x8*)&sm.g2.Ws[row][c8 * 8] =
                *(const u16x8*)(Wm + (size_t)row * 256 + c0 + c8 * 8);
        }
        __syncthreads();
        u16x8 t;
        #pragma unroll
        for (int i = 0; i < 8; ++i) t[i] = sm.g2.NAs[wr * 16 + ln][c0 + q * 8 + i];
        bf16x8 af = __builtin_bit_cast(bf16x8, t);
        #pragma unroll
        for (int nt = 0; nt < 8; ++nt) {
            bf16x8 bb = ldfrag(&sm.g2.Ws[wc * 128 + nt * 16 + ln][q * 8]);
            acc2[nt] = __builtin_amdgcn_mfma_f32_16x16x32_bf16(af, bb, acc2[nt], 0, 0, 0);
        }
        __syncthreads();
    }

    // ---- epilogue: bias + residual, fp32 output
    #pragma unroll
    for (int nt = 0; nt < 8; ++nt) {
        int n = wc * 128 + nt * 16 + ln;
        float bias = Bv[n];
        #pragma unroll
        for (int r = 0; r < 4; ++r) {
            int mi = wr * 16 + q * 4 + r;                 // [0,32)
            int row = (m0 + mi) * 16 + s;                 // [0,2048) within batch
            size_t idx = ((size_t)batch * 2048 + row) * 256 + n;
            O[idx] = acc2[nt][r] + bias + R[idx];
        }
    }
}

extern "C" void kernel_launch(void* const* d_in, const int* in_sizes, int n_in,
                              void* d_out, int out_size, void* d_ws, size_t ws_size,
                              hipStream_t stream)
{
    Params p;
    p.detect = (const float*)d_in[0];
    p.aim    = (const float*)d_in[1];
    p.g_w  = (const float*)d_in[2];  p.g_b  = (const float*)d_in[3];
    p.g2_w = (const float*)d_in[4];  p.g2_b = (const float*)d_in[5];
    p.th_w = (const float*)d_in[6];  p.th_b = (const float*)d_in[7];
    p.ph_w = (const float*)d_in[8];  p.ph_b = (const float*)d_in[9];
    p.W_w  = (const float*)d_in[10]; p.W_b  = (const float*)d_in[11];
    p.Q_w  = (const float*)d_in[12]; p.Q_b  = (const float*)d_in[13];

    const size_t TOT = 8192L * 256;   // 2,097,152 elems per tensor

    unsigned short* ws16 = (unsigned short*)d_ws;
    p.Wbf = ws16;                    // [2][65536] bf16: W, Q
    p.T   = p.Wbf + 2 * 65536;
    p.P   = p.T  + TOT;
    p.Gd  = p.P  + TOT;
    p.Ga  = p.Gd + TOT;
    p.Spart = (float*)(p.Ga + TOT);  // [2][4][16][128][128] fp32 = 8.4 MB

    p.out_det = (float*)d_out;
    p.out_aim = p.out_det + TOT;

    linall_kernel<<<dim3(2, 64, 2), 256, 0, stream>>>(p);
    spart_kernel<<<dim3(256), 256, 0, stream>>>(p);
    outfused_kernel<<<dim3(512), 256, 0, stream>>>(p);
}